// Round 5
// baseline (48662.744 us; speedup 1.0000x reference)
//
#include <hip/hip_runtime.h>
#include <cstdint>

typedef unsigned short u16;
typedef unsigned u32;
typedef unsigned long long u64;
typedef __attribute__((ext_vector_type(8))) short bf16x8;
typedef __attribute__((ext_vector_type(4))) float f32x4;

#define S_LEN 1000

// ---------------- ws layout (bytes) ----------------
#define OFF_HALL   0ull                         // (1001*64, 512) bf16 hidden states; xb aliases here (dead before scan)
#define SZ_HALL    (1001ull*64*512*2)
#define OFF_WCAT   (OFF_HALL + SZ_HALL)         // (1536, 448) bf16  [Wh;Wz;Wr] K-padded
#define SZ_WCAT    (1536ull*448*2)
#define OFF_WFB    (OFF_WCAT + SZ_WCAT)         // (1024, 512) bf16  Wf row-padded
#define SZ_WFB     (1024ull*512*2)
#define OFF_GSUM   (OFF_WFB + SZ_WFB)
#define OFF_GSQ    (OFF_GSUM + 1536*4)
#define OFF_AALL   (OFF_GSQ  + 1536*4)
#define OFF_CALL   (OFF_AALL + 1536*4)
#define OFF_SSUM   (OFF_CALL + 1536*4)
#define OFF_SSQ    (OFF_SSUM + 1024*4)
#define OFF_AF     (OFF_SSQ  + 1024*4)
#define OFF_CF     (OFF_AF   + 1024*4)
#define STATS_ZERO_BYTES (OFF_CF + 1024*4 - OFF_SSUM)

// ---------------- helpers ----------------
__device__ __forceinline__ float bf2f(u16 u) {
  union { unsigned u; float f; } v; v.u = ((unsigned)u) << 16; return v.f;
}
__device__ __forceinline__ u16 f2bf(float f) {   // RNE
  union { float f; unsigned u; } v; v.f = f;
  unsigned r = (v.u + 0x7fffu + ((v.u >> 16) & 1u)) >> 16;
  return (u16)r;
}
__device__ __forceinline__ float sigm(float x) { return 1.f / (1.f + __expf(-x)); }
__device__ __forceinline__ float tanh_(float x) {
  float e = __expf(-2.f * fabsf(x));
  float r = (1.f - e) / (1.f + e);
  return x >= 0.f ? r : -r;
}

// async global->LDS, 16B/lane
__device__ __forceinline__ void stage16(const u16* g, u16* l) {
  __builtin_amdgcn_global_load_lds((const __attribute__((address_space(1))) unsigned int*)(g),
                                   (__attribute__((address_space(3))) unsigned int*)(l), 16, 0, 0);
}

// ---------------- fp32 -> bf16 converts with padding ----------------
__global__ void cvt_pad(const float* __restrict__ src, u16* __restrict__ dst, int incols, int outcols) {
  int r = blockIdx.x, ci = threadIdx.x;
  float v = (ci < incols) ? src[(size_t)r * incols + ci] : 0.f;
  dst[(size_t)r * outcols + ci] = f2bf(v);
}
__global__ void cvt_wf(const float* __restrict__ src, u16* __restrict__ dst) {
  int r = blockIdx.x, ci = threadIdx.x;     // grid 1024, block 512; rows >= 1000 are zero pad
  float v = (r < 1000) ? src[(size_t)r * 512 + ci] : 0.f;
  dst[(size_t)r * 512 + ci] = f2bf(v);
}
// U matrices (512x512 f32 each) -> bf16, packed [Uz; Ur; Uh]
__global__ void cvt_u(const float* __restrict__ Uz, const float* __restrict__ Ur,
                      const float* __restrict__ Uh, u16* __restrict__ dst) {
  const int m = blockIdx.y;                 // 0=Uz, 1=Ur, 2=Uh
  const int row = blockIdx.x;               // 0..511
  const int c = threadIdx.x;                // 512
  const float* src = m == 0 ? Uz : m == 1 ? Ur : Uh;
  dst[((size_t)m * 512 + row) * 512 + c] = f2bf(src[(size_t)row * 512 + c]);
}

// ---------------- bf16 GEMM  C = A[M,K] @ B[N,K]^T  (128x128 tile, BK=32) ----------------
template<int MODE>
__global__ __launch_bounds__(256, 1) void gemm_bt(const u16* __restrict__ A, const u16* __restrict__ B,
                                                  void* __restrict__ Cout, int K, int ldc, int nlimit) {
  __shared__ __align__(16) u16 smem[16 * 512];
  const int bm = blockIdx.x * 128;
  const int bn = blockIdx.y * 128;
  const int tid = threadIdx.x;
  const int w = tid >> 6;
  const int lane = tid & 63;
  const int r = lane & 15;
  const int q = lane >> 4;
  const int wm = w & 1, wn = w >> 1;

  f32x4 acc[4][4];
#pragma unroll
  for (int i = 0; i < 4; ++i)
#pragma unroll
    for (int j = 0; j < 4; ++j) acc[i][j] = (f32x4){0.f, 0.f, 0.f, 0.f};

  const u16* gA0 = A + (size_t)(bm + w * 16 + r) * K + q * 8;
  const u16* gA1 = A + (size_t)(bm + (w + 4) * 16 + r) * K + q * 8;
  const u16* gB0 = B + (size_t)(bn + w * 16 + r) * K + q * 8;
  const u16* gB1 = B + (size_t)(bn + (w + 4) * 16 + r) * K + q * 8;
  u16* As = smem;
  u16* Bs = smem + 8 * 512;

  for (int k0 = 0; k0 < K; k0 += 32) {
    stage16(gA0 + k0, As + w * 512);
    stage16(gA1 + k0, As + (w + 4) * 512);
    stage16(gB0 + k0, Bs + w * 512);
    stage16(gB1 + k0, Bs + (w + 4) * 512);
    __syncthreads();
    bf16x8 af[4], bf_[4];
#pragma unroll
    for (int mi = 0; mi < 4; ++mi) af[mi] = *(const bf16x8*)(As + (wm * 4 + mi) * 512 + lane * 8);
#pragma unroll
    for (int ni = 0; ni < 4; ++ni) bf_[ni] = *(const bf16x8*)(Bs + (wn * 4 + ni) * 512 + lane * 8);
#pragma unroll
    for (int mi = 0; mi < 4; ++mi)
#pragma unroll
      for (int ni = 0; ni < 4; ++ni)
        acc[mi][ni] = __builtin_amdgcn_mfma_f32_16x16x32_bf16(af[mi], bf_[ni], acc[mi][ni], 0, 0, 0);
    __syncthreads();
  }
  const int row0 = bm + wm * 64;
  const int col0 = bn + wn * 64;
#pragma unroll
  for (int mi = 0; mi < 4; ++mi)
#pragma unroll
    for (int ni = 0; ni < 4; ++ni) {
      int cc = col0 + ni * 16 + r;            // C/D: col=lane&15, row=(lane>>4)*4+reg
      int rr = row0 + mi * 16 + q * 4;
      if (MODE == 1) {
#pragma unroll
        for (int i = 0; i < 4; ++i)
          if (cc < nlimit) ((float*)Cout)[(size_t)(rr + i) * ldc + cc] = acc[mi][ni][i];
      } else {  // transposed bf16: CT[cc][rr..rr+3] as one 8B store
        u64 pk = (u64)f2bf(acc[mi][ni][0]) | ((u64)f2bf(acc[mi][ni][1]) << 16) |
                 ((u64)f2bf(acc[mi][ni][2]) << 32) | ((u64)f2bf(acc[mi][ni][3]) << 48);
        *(u64*)((u16*)Cout + (size_t)cc * ldc + rr) = pk;
      }
    }
}

// ---------------- per-row sum/sumsq over gatesT (1536 rows x 64000) ----------------
__global__ __launch_bounds__(256, 1) void rowstats(const u16* __restrict__ G,
                                                   float* __restrict__ sum, float* __restrict__ sumsq) {
  const int n = blockIdx.x;
  const u16* row = G + (size_t)n * 64000;
  float s = 0.f, ss = 0.f;
  for (int idx = threadIdx.x * 8; idx < 64000; idx += 2048) {
    union { bf16x8 v; u16 e[8]; } u;
    u.v = *(const bf16x8*)(row + idx);
#pragma unroll
    for (int e = 0; e < 8; ++e) { float f = bf2f(u.e[e]); s += f; ss += f * f; }
  }
#pragma unroll
  for (int o = 32; o > 0; o >>= 1) { s += __shfl_xor(s, o); ss += __shfl_xor(ss, o); }
  __shared__ float ls[4], lss[4];
  if ((threadIdx.x & 63) == 0) { ls[threadIdx.x >> 6] = s; lss[threadIdx.x >> 6] = ss; }
  __syncthreads();
  if (threadIdx.x == 0) {
    sum[n]   = ls[0] + ls[1] + ls[2] + ls[3];
    sumsq[n] = lss[0] + lss[1] + lss[2] + lss[3];
  }
}

// ---------------- per-column sum/sumsq over fp32 scores (64000 x 1000) ----------------
__global__ __launch_bounds__(256, 1) void colstats_f32(const float* __restrict__ X, int ld, int ncols,
                                                       float* __restrict__ sum, float* __restrict__ sumsq) {
  const int col = blockIdx.x * 128 + (threadIdx.x & 127);
  const int half = threadIdx.x >> 7;
  const int r0 = blockIdx.y * 2000;
  float s = 0.f, ss = 0.f;
  if (col < ncols) {
    for (int rr = r0 + half; rr < r0 + 2000; rr += 2) {
      float v = X[(size_t)rr * ld + col]; s += v; ss += v * v;
    }
  }
  __shared__ float ls[128], lss[128];
  if (half) { ls[threadIdx.x & 127] = s; lss[threadIdx.x & 127] = ss; }
  __syncthreads();
  if (!half && col < ncols) {
    s += ls[threadIdx.x]; ss += lss[threadIdx.x];
    atomicAdd(&sum[col], s); atomicAdd(&sumsq[col], ss);
  }
}

__global__ void fin_gate(const float* __restrict__ sum, const float* __restrict__ sq,
                         const float* gh, const float* bh, const float* gz, const float* bz,
                         const float* gr, const float* br, float* __restrict__ a, float* __restrict__ c) {
  int j = blockIdx.x * 256 + threadIdx.x;
  if (j >= 1536) return;
  float m = sum[j] * (1.f / 64000.f);
  float v = sq[j] * (1.f / 64000.f) - m * m;
  int seg = j >> 9, jj = j & 511;
  float gg = seg == 0 ? gh[jj] : seg == 1 ? gz[jj] : gr[jj];
  float bb = seg == 0 ? bh[jj] : seg == 1 ? bz[jj] : br[jj];
  float aa = gg * rsqrtf(v + 1e-5f);
  a[j] = aa; c[j] = bb - m * aa;
}

__global__ void fin_score(const float* __restrict__ sum, const float* __restrict__ sq,
                          const float* __restrict__ gfp, const float* __restrict__ bfp,
                          float* __restrict__ a, float* __restrict__ c) {
  int j = blockIdx.x * 256 + threadIdx.x;
  if (j >= 1000) return;
  float m = sum[j] * (1.f / 64000.f);
  float v = sq[j] * (1.f / 64000.f) - m * m;
  float aa = gfp[j] * rsqrtf(v + 1e-5f);
  a[j] = aa; c[j] = bfp[j] - m * aa;
}

// ---------------- batch-split GRU scan: 4 WGs x 16 batch rows, zero cross-WG traffic ----------------
// The recurrence couples only within a batch row, so each WG owns 16 batch rows and
// computes the FULL 512-dim hidden state: h and r*h live in LDS, the two per-step
// exchanges are __syncthreads() instead of device-scope LLC round trips. U matrices
// (1.5 MB bf16, step-invariant addresses) stream from L2 as MFMA B-fragments.
// Wave w owns H-columns [w*128,(w+1)*128); lane: r=lane&15 (A-row / B-row), q=lane>>4.
__global__ __launch_bounds__(256, 1) void scan_kernel(
    const u16* __restrict__ gatesT,              // (1536, 64000) bf16 transposed projections (in d_out)
    const u16* __restrict__ Ub,                  // [3][512][512] bf16: Uz, Ur, Uh (in d_out past gatesT)
    const float* __restrict__ acoef, const float* __restrict__ ccoef,
    u16* __restrict__ hall) {                    // (1001*64,512) bf16, rows t*64+b
  __shared__ __align__(16) u16 h_buf[16][520];   // h_{t-1}, rows = batch-in-group (pad 520: 2-way banks)
  __shared__ __align__(16) u16 rh_buf[16][520];  // r*h
  const int grp = blockIdx.x;                    // batch rows [grp*16, grp*16+16)
  const int tid = threadIdx.x;
  const int w = tid >> 6;
  const int lane = tid & 63;
  const int r = lane & 15;
  const int q = lane >> 4;
  const int jw = w * 128;

  for (int idx = tid; idx < 16 * 520 / 2; idx += 256) ((u32*)h_buf)[idx] = 0;   // h_0 = 0

  // per-lane BN coefs (constant over t): index j = jw + n*16 + r
  float caz[8], ccz[8], car[8], ccr[8], cah[8], cch[8];
#pragma unroll
  for (int n = 0; n < 8; ++n) {
    int j = jw + n * 16 + r;
    caz[n] = acoef[512 + j];  ccz[n] = ccoef[512 + j];
    car[n] = acoef[1024 + j]; ccr[n] = ccoef[1024 + j];
    cah[n] = acoef[j];        cch[n] = ccoef[j];
  }
  const u16* Uzb = Ub;
  const u16* Urb = Ub + 512 * 512;
  const u16* Uhb = Ub + 2 * 512 * 512;
  // gate row bases: gatesT row j (H at j, Z at 512+j, R at 1024+j), col (t-1)*64 + b
  const u16* gH = gatesT + (size_t)(jw + r) * 64000 + grp * 16 + q * 4;
  const u16* gZ = gatesT + (size_t)(512 + jw + r) * 64000 + grp * 16 + q * 4;
  const u16* gR = gatesT + (size_t)(1024 + jw + r) * 64000 + grp * 16 + q * 4;

  float hp[8][4];                                // own h C-frags: (batch q*4+i, col jw+n*16+r)
#pragma unroll
  for (int n = 0; n < 8; ++n)
#pragma unroll
    for (int i = 0; i < 4; ++i) hp[n][i] = 0.f;

  __syncthreads();

  for (int t = 1; t <= S_LEN; ++t) {
    const size_t tof = (size_t)(t - 1) * 64;
    // this step's gate inputs (issued early, consumed after the matmuls)
    u64 wzq[8], wrq[8], whq[8];
#pragma unroll
    for (int n = 0; n < 8; ++n) {
      wzq[n] = *(const u64*)(gZ + (size_t)n * (16 * 64000) + tof);
      wrq[n] = *(const u64*)(gR + (size_t)n * (16 * 64000) + tof);
      whq[n] = *(const u64*)(gH + (size_t)n * (16 * 64000) + tof);
    }
    // A-frags: h_{t-1}[batch r][k = ks*32 + q*8 ..]
    bf16x8 ah[16];
#pragma unroll
    for (int ks = 0; ks < 16; ++ks)
      ah[ks] = *(const bf16x8*)(&h_buf[r][ks * 32 + q * 8]);

    // ---- z & r matmuls (z/r interleaved: MFMA dep-distance 2) ----
    f32x4 accz[8], accr[8];
#pragma unroll
    for (int n = 0; n < 8; ++n) { accz[n] = (f32x4){0.f,0.f,0.f,0.f}; accr[n] = (f32x4){0.f,0.f,0.f,0.f}; }
#pragma unroll
    for (int n = 0; n < 8; ++n) {
      const u16* bzp = Uzb + (size_t)(jw + n * 16 + r) * 512 + q * 8;
      const u16* brp = Urb + (size_t)(jw + n * 16 + r) * 512 + q * 8;
      bf16x8 bz[16], br[16];
#pragma unroll
      for (int ks = 0; ks < 16; ++ks) {
        bz[ks] = *(const bf16x8*)(bzp + ks * 32);
        br[ks] = *(const bf16x8*)(brp + ks * 32);
      }
#pragma unroll
      for (int ks = 0; ks < 16; ++ks) {
        accz[n] = __builtin_amdgcn_mfma_f32_16x16x32_bf16(ah[ks], bz[ks], accz[n], 0, 0, 0);
        accr[n] = __builtin_amdgcn_mfma_f32_16x16x32_bf16(ah[ks], br[ks], accr[n], 0, 0, 0);
      }
    }
    // r gate -> rh into LDS (paired 4B writes); z gate kept in registers
    float zvv[8][4];
#pragma unroll
    for (int n = 0; n < 8; ++n) {
      const int j = jw + n * 16 + r;
#pragma unroll
      for (int i = 0; i < 4; ++i) {
        float wr_ = bf2f((u16)(wrq[n] >> (16 * i)));
        float rv = sigm(accr[n][i] + wr_ * car[n] + ccr[n]);
        u16 rhb = f2bf(rv * hp[n][i]);
        float partner = __shfl_xor(bf2f(rhb), 1);
        if ((r & 1) == 0)
          *(u32*)(&rh_buf[q * 4 + i][j]) = (u32)rhb | ((u32)f2bf(partner) << 16);
        float wz_ = bf2f((u16)(wzq[n] >> (16 * i)));
        zvv[n][i] = sigm(accz[n][i] + wz_ * caz[n] + ccz[n]);
      }
    }
    __syncthreads();

    // ---- hcand matmul from rh (tile-pair interleave: dep-distance 2) ----
    bf16x8 a2[16];
#pragma unroll
    for (int ks = 0; ks < 16; ++ks)
      a2[ks] = *(const bf16x8*)(&rh_buf[r][ks * 32 + q * 8]);
    f32x4 acch[8];
#pragma unroll
    for (int n = 0; n < 8; ++n) acch[n] = (f32x4){0.f,0.f,0.f,0.f};
#pragma unroll
    for (int np = 0; np < 8; np += 2) {
      const u16* b0p = Uhb + (size_t)(jw + np * 16 + r) * 512 + q * 8;
      const u16* b1p = b0p + 16 * 512;
      bf16x8 b0[16], b1[16];
#pragma unroll
      for (int ks = 0; ks < 16; ++ks) {
        b0[ks] = *(const bf16x8*)(b0p + ks * 32);
        b1[ks] = *(const bf16x8*)(b1p + ks * 32);
      }
#pragma unroll
      for (int ks = 0; ks < 16; ++ks) {
        acch[np]     = __builtin_amdgcn_mfma_f32_16x16x32_bf16(a2[ks], b0[ks], acch[np], 0, 0, 0);
        acch[np + 1] = __builtin_amdgcn_mfma_f32_16x16x32_bf16(a2[ks], b1[ks], acch[np + 1], 0, 0, 0);
      }
    }
    // ---- h_t: blend, carry own frags, publish to LDS ----
#pragma unroll
    for (int n = 0; n < 8; ++n) {
      const int j = jw + n * 16 + r;
#pragma unroll
      for (int i = 0; i < 4; ++i) {
        float wh_ = bf2f((u16)(whq[n] >> (16 * i)));
        float hc = tanh_(acch[n][i] + wh_ * cah[n] + cch[n]);
        float hn = zvv[n][i] * hp[n][i] + (1.f - zvv[n][i]) * hc;
        u16 hb = f2bf(hn);
        hp[n][i] = bf2f(hb);
        float partner = __shfl_xor(bf2f(hb), 1);
        if ((r & 1) == 0)
          *(u32*)(&h_buf[q * 4 + i][j]) = (u32)hb | ((u32)f2bf(partner) << 16);
      }
    }
    __syncthreads();

    // coalesced hall store (classifier input; off critical path, safe before next
    // h_buf write which happens only after the NEXT step's first barrier)
    u16* hrow = hall + (size_t)(t * 64 + grp * 16) * 512;
#pragma unroll
    for (int it = 0; it < 4; ++it) {
      const int row = it * 4 + w;
      bf16x8 v = *(const bf16x8*)(&h_buf[row][lane * 8]);
      *(bf16x8*)(hrow + (size_t)row * 512 + lane * 8) = v;
    }
  }
}

// ---------------- BN + log_softmax, in place on fp32 scores ----------------
__global__ __launch_bounds__(256, 1) void logsoftmax_k(float* __restrict__ S,
                                                       const float* __restrict__ a, const float* __restrict__ c) {
  __shared__ float as_[1000], cs_[1000];
  for (int i = threadIdx.x; i < 1000; i += 256) { as_[i] = a[i]; cs_[i] = c[i]; }
  __syncthreads();
  const int w = threadIdx.x >> 6, lane = threadIdx.x & 63;
  for (int it = 0; it < 4; ++it) {
    const int row = blockIdx.x * 16 + it * 4 + w;
    float* Srow = S + (size_t)row * 1000;
    float tv[16];
    float mx = -3.0e38f;
#pragma unroll
    for (int qq = 0; qq < 16; ++qq) {
      int j = lane + qq * 64;
      float v = -3.0e38f;
      if (j < 1000) v = as_[j] * Srow[j] + cs_[j];
      tv[qq] = v;
      mx = fmaxf(mx, v);
    }
#pragma unroll
    for (int o = 32; o > 0; o >>= 1) mx = fmaxf(mx, __shfl_xor(mx, o));
    float sm = 0.f;
#pragma unroll
    for (int qq = 0; qq < 16; ++qq) sm += __expf(tv[qq] - mx);
#pragma unroll
    for (int o = 32; o > 0; o >>= 1) sm += __shfl_xor(sm, o);
    float lse = mx + __logf(sm);
#pragma unroll
    for (int qq = 0; qq < 16; ++qq) {
      int j = lane + qq * 64;
      if (j < 1000) Srow[j] = tv[qq] - lse;
    }
  }
}

// ---------------- launch ----------------
extern "C" void kernel_launch(void* const* d_in, const int* in_sizes, int n_in,
                              void* d_out, int out_size, void* d_ws, size_t ws_size,
                              hipStream_t stream) {
  const float* x  = (const float*)d_in[0];
  const float* Wh = (const float*)d_in[1];
  const float* Wz = (const float*)d_in[2];
  const float* Wr = (const float*)d_in[3];
  const float* Uh = (const float*)d_in[4];
  const float* Uz = (const float*)d_in[5];
  const float* Ur = (const float*)d_in[6];
  const float* gh = (const float*)d_in[7];
  const float* bh = (const float*)d_in[8];
  const float* gz = (const float*)d_in[9];
  const float* bz = (const float*)d_in[10];
  const float* gr = (const float*)d_in[11];
  const float* br = (const float*)d_in[12];
  const float* Wf = (const float*)d_in[13];
  const float* gf = (const float*)d_in[14];
  const float* bfp = (const float*)d_in[15];

  uint8_t* ws = (uint8_t*)d_ws;
  u16* hall = (u16*)(ws + OFF_HALL);
  u16* xb   = (u16*)(ws + OFF_HALL);   // alias: xb dead before hall is written
  u16* wcat = (u16*)(ws + OFF_WCAT);
  u16* wfb  = (u16*)(ws + OFF_WFB);
  float* gsum = (float*)(ws + OFF_GSUM);
  float* gsq  = (float*)(ws + OFF_GSQ);
  float* aall = (float*)(ws + OFF_AALL);
  float* call = (float*)(ws + OFF_CALL);
  float* ssum = (float*)(ws + OFF_SSUM);
  float* ssq  = (float*)(ws + OFF_SSQ);
  float* af   = (float*)(ws + OFF_AF);
  float* cf   = (float*)(ws + OFF_CF);

  u16* gatesT = (u16*)d_out;            // (1536, 64000) bf16, dead after scan
  u16* Ub = (u16*)d_out + (size_t)1536 * 64000;   // [3][512][512] bf16 in d_out past gatesT
  float* scores = (float*)d_out;        // (64000,1000) fp32, overwrites everything later

  hipMemsetAsync(ws + OFF_SSUM, 0, (size_t)STATS_ZERO_BYTES, stream);

  cvt_pad<<<dim3(64000), dim3(448), 0, stream>>>(x, xb, 440, 448);
  cvt_pad<<<dim3(512), dim3(448), 0, stream>>>(Wh, wcat, 440, 448);
  cvt_pad<<<dim3(512), dim3(448), 0, stream>>>(Wz, wcat + 512 * 448, 440, 448);
  cvt_pad<<<dim3(512), dim3(448), 0, stream>>>(Wr, wcat + 1024 * 448, 440, 448);
  cvt_wf<<<dim3(1024), dim3(512), 0, stream>>>(Wf, wfb);
  cvt_u<<<dim3(512, 3), dim3(512), 0, stream>>>(Uz, Ur, Uh, Ub);

  gemm_bt<2><<<dim3(500, 12), dim3(256), 0, stream>>>(xb, wcat, (void*)gatesT, 448, 64000, 1536);

  rowstats<<<dim3(1536), dim3(256), 0, stream>>>(gatesT, gsum, gsq);
  fin_gate<<<dim3(6), dim3(256), 0, stream>>>(gsum, gsq, gh, bh, gz, bz, gr, br, aall, call);

  scan_kernel<<<dim3(4), dim3(256), 0, stream>>>(gatesT, Ub, aall, call, hall);

  gemm_bt<1><<<dim3(500, 8), dim3(256), 0, stream>>>(hall + 64 * 512, wfb, (void*)scores, 512, 1000, 1000);

  colstats_f32<<<dim3(8, 32), dim3(256), 0, stream>>>(scores, 1000, 1000, ssum, ssq);
  fin_score<<<dim3(4), dim3(256), 0, stream>>>(ssum, ssq, gf, bfp, af, cf);

  logsoftmax_k<<<dim3(4000), dim3(256), 0, stream>>>(scores, af, cf);
}